// Round 1
// baseline (905.144 us; speedup 1.0000x reference)
//
#include <hip/hip_runtime.h>

// SuperPixelMeanEmbed: x = X@W.T + b (M=32, N=K=12288), then per-superpixel
// channel means. Segment-mean is linear -> scatter partial-K GEMM results
// straight into segment sums with atomics; never materialize x.
//
// Roofline: W = 604 MB f32 read once -> ~96 us HBM floor @6.3 TB/s.

namespace {
constexpr int BATCH = 32;
constexpr int CH    = 3;
constexpr int HWPIX = 4096;     // H*W = 64*64
constexpr int DDIM  = 12288;    // C*H*W
constexpr int KDIM  = 12288;
constexpr int NSEG  = 196;

constexpr int DT     = 256;     // W rows per block (one per thread)
constexpr int KT     = 32;      // k per LDS chunk
constexpr int KSPLIT = 16;      // k-range splits across blockIdx.y
constexpr int KC     = KDIM / KSPLIT;  // 768 k's per block
}

// ---------------- per-image superpixel pixel counts ----------------
__global__ __launch_bounds__(256) void seg_count_kernel(
    const int* __restrict__ seg, float* __restrict__ cnt)
{
    __shared__ int hist[NSEG];
    const int b = blockIdx.x;
    for (int i = threadIdx.x; i < NSEG; i += 256) hist[i] = 0;
    __syncthreads();
    const int* sm = seg + b * HWPIX;
    for (int p = threadIdx.x; p < HWPIX; p += 256)
        atomicAdd(&hist[sm[p]], 1);
    __syncthreads();
    for (int s = threadIdx.x; s < NSEG; s += 256)
        cnt[b * NSEG + s] = (float)hist[s];
}

// ---------------- fused skinny-GEMM + segment scatter ----------------
// grid = (DDIM/DT, KSPLIT); block = 256. Thread t owns W row d0+t, holds
// acc[b] = partial dot(X[b, krange], W[d, krange]) for all 32 images.
__global__ __launch_bounds__(256, 3) void gemm_scatter_kernel(
    const float* __restrict__ Xg, const float* __restrict__ Wg,
    const float* __restrict__ bias, const int* __restrict__ seg,
    float* __restrict__ sums)
{
    // LDS tile: 256 rows x 32 floats, stored as float4 slots with XOR swizzle
    // (slot = j4 ^ (row&7)) -> conflict-free ds_read_b128 at row stride 128B.
    __shared__ float lds[DT * KT];
    float4* lds4 = reinterpret_cast<float4*>(lds);

    const int t     = threadIdx.x;
    const int d0    = blockIdx.x * DT;
    const int kbase = blockIdx.y * KC;

    float acc[BATCH];
#pragma unroll
    for (int b = 0; b < BATCH; ++b) acc[b] = 0.f;

    for (int ch = 0; ch < KC / KT; ++ch) {
        const int k0 = kbase + ch * KT;
        __syncthreads();   // protect previous chunk's reads
        // stage W[d0..d0+255][k0..k0+31] coalesced: 8 lanes x float4 = 128B/row
#pragma unroll
        for (int r = 0; r < 8; ++r) {
            const int i  = (t >> 3) + r * 32;   // row within tile
            const int j4 = t & 7;               // float4 slot within row
            const float4 v = *reinterpret_cast<const float4*>(
                Wg + (size_t)(d0 + i) * KDIM + k0 + j4 * 4);
            lds4[i * 8 + (j4 ^ (i & 7))] = v;
        }
        __syncthreads();
        // compute: thread t reads its own row t; X reads are wave-uniform
        // (no lane dependence) -> scalar cache s_loads.
#pragma unroll
        for (int kk4 = 0; kk4 < 8; ++kk4) {
            const float4 w = lds4[t * 8 + (kk4 ^ (t & 7))];
            const int kx = k0 + kk4 * 4;
#pragma unroll
            for (int b = 0; b < BATCH; ++b) {
                const float* xb = Xg + b * KDIM + kx;
                float a = acc[b];
                a = fmaf(xb[0], w.x, a);
                a = fmaf(xb[1], w.y, a);
                a = fmaf(xb[2], w.z, a);
                a = fmaf(xb[3], w.w, a);
                acc[b] = a;
            }
        }
    }

    // epilogue: scatter partial sums into segment accumulators
    const int d = d0 + t;
    const int c = d >> 12;            // d / 4096
    const int p = d & (HWPIX - 1);    // d % 4096
    const float bv = (blockIdx.y == 0) ? bias[d] : 0.f;
#pragma unroll
    for (int b = 0; b < BATCH; ++b) {
        const int s = seg[b * HWPIX + p];
        atomicAdd(&sums[(b * NSEG + s) * CH + c], acc[b] + bv);
    }
}

// ---------------- finalize: mean = sum / max(cnt,1), in place ----------------
__global__ __launch_bounds__(256) void finalize_kernel(
    float* __restrict__ sums, const float* __restrict__ cnt)
{
    const int i = blockIdx.x * 256 + threadIdx.x;
    if (i >= BATCH * NSEG * CH) return;
    const int bs = i / CH;
    sums[i] = sums[i] / fmaxf(cnt[bs], 1.f);
}

extern "C" void kernel_launch(void* const* d_in, const int* in_sizes, int n_in,
                              void* d_out, int out_size, void* d_ws, size_t ws_size,
                              hipStream_t stream) {
    const float* X    = (const float*)d_in[0];
    const float* W    = (const float*)d_in[1];
    const float* bias = (const float*)d_in[2];
    const int*   seg  = (const int*)d_in[3];
    float* out = (float*)d_out;           // accumulates segment sums, then means
    float* cnt = (float*)d_ws;            // [32*196] pixel counts

    // zero the accumulator (harness poisons d_out; no re-poison between replays)
    hipMemsetAsync(out, 0, (size_t)BATCH * NSEG * CH * sizeof(float), stream);

    seg_count_kernel<<<BATCH, 256, 0, stream>>>(seg, cnt);

    dim3 grid(DDIM / DT, KSPLIT);
    gemm_scatter_kernel<<<grid, 256, 0, stream>>>(X, W, bias, seg, out);

    finalize_kernel<<<(BATCH * NSEG * CH + 255) / 256, 256, 0, stream>>>(out, cnt);
}

// Round 2
// 408.867 us; speedup vs baseline: 2.2138x; 2.2138x over previous
//
#include <hip/hip_runtime.h>

// SuperPixelMeanEmbed: x = X@W.T + b (M=32, N=K=12288), then per-superpixel
// channel means. W = 604 MB f32 read once -> ~96 us HBM floor.
//
// R2 design: latency-bound fix. No LDS in the GEMM (no barriers); lane<->row
// mapping so each W 64B line is consumed whole by one lane; X pre-transposed
// so a wave's batch-group slice is one s_load_dwordx8 (wave-uniform address);
// split-K partials accumulated via uncontended atomics into x[b,d]; segment
// aggregation done per-image in LDS with zero global atomics.

namespace {
constexpr int BATCH = 32;
constexpr int CH    = 3;
constexpr int HWPIX = 4096;     // 64*64
constexpr int DDIM  = 12288;
constexpr int KDIM  = 12288;
constexpr int NSEG  = 196;

constexpr int KSPLIT = 12;
constexpr int KRANGE = KDIM / KSPLIT;   // 1024
constexpr int KT     = 16;              // k per register chunk
constexpr int NCHUNK = KRANGE / KT;     // 64
}

// ---------------- X transpose: Xt[k][b] = X[b][k] ----------------
// thread -> one float4 of Xt: k = tid>>3, b4 = tid&7 (batches b4*4..+3).
__global__ __launch_bounds__(256) void transpose_x_kernel(
    const float* __restrict__ X, float* __restrict__ Xt)
{
    const int tid = blockIdx.x * 256 + threadIdx.x;
    const int k   = tid >> 3;
    const int b4  = tid & 7;
    float4 v;
    v.x = X[(size_t)(b4 * 4 + 0) * KDIM + k];
    v.y = X[(size_t)(b4 * 4 + 1) * KDIM + k];
    v.z = X[(size_t)(b4 * 4 + 2) * KDIM + k];
    v.w = X[(size_t)(b4 * 4 + 3) * KDIM + k];
    *reinterpret_cast<float4*>(Xt + (size_t)k * BATCH + b4 * 4) = v;
}

// ---------------- skinny GEMM, split-K, no LDS ----------------
// grid = (DDIM/64, KSPLIT); block = 256 = 4 waves.
// lane = row (d0+lane); wave w handles batches w*8..w*8+7.
__global__ __launch_bounds__(256, 8) void gemm_kernel(
    const float* __restrict__ Wg, const float* __restrict__ Xt,
    float* __restrict__ xout)
{
    const int lane = threadIdx.x & 63;
    const int bg   = __builtin_amdgcn_readfirstlane(threadIdx.x >> 6); // 0..3
    const int d    = blockIdx.x * 64 + lane;
    const int kb   = blockIdx.y * KRANGE;

    const float4* wrow = reinterpret_cast<const float4*>(
        Wg + (size_t)d * KDIM + kb);                 // 4 float4 per KT chunk
    const float* xt = Xt + (size_t)kb * BATCH + bg * 8;  // wave-uniform

    float acc[8];
#pragma unroll
    for (int j = 0; j < 8; ++j) acc[j] = 0.f;

#define WELT(buf, kk) ( ((kk)&3)==0 ? buf[(kk)>>2].x \
                      : ((kk)&3)==1 ? buf[(kk)>>2].y \
                      : ((kk)&3)==2 ? buf[(kk)>>2].z : buf[(kk)>>2].w )

#define FMA_CHUNK(buf, ch)                                             \
    {                                                                  \
        const float* xc = xt + (size_t)(ch) * KT * BATCH;              \
        _Pragma("unroll")                                              \
        for (int kk = 0; kk < KT; ++kk) {                              \
            const float wv = WELT(buf, kk);                            \
            _Pragma("unroll")                                          \
            for (int j = 0; j < 8; ++j)                                \
                acc[j] = fmaf(wv, xc[kk * BATCH + j], acc[j]);         \
        }                                                              \
    }

    float4 wb0[4], wb1[4];
#pragma unroll
    for (int q = 0; q < 4; ++q) wb0[q] = wrow[q];

    // register ping-pong: prefetch next chunk's W while FMAing current
    for (int ch = 0; ch < NCHUNK; ch += 2) {
        const int c1 = (ch + 1 < NCHUNK) ? ch + 1 : NCHUNK - 1;
        const int c2 = (ch + 2 < NCHUNK) ? ch + 2 : NCHUNK - 1;
#pragma unroll
        for (int q = 0; q < 4; ++q) wb1[q] = wrow[c1 * 4 + q];
        FMA_CHUNK(wb0, ch)
#pragma unroll
        for (int q = 0; q < 4; ++q) wb0[q] = wrow[c2 * 4 + q];
        FMA_CHUNK(wb1, ch + 1)
    }

    // epilogue: wave covers full 64B lines of x[b][d0..d0+63]
#pragma unroll
    for (int j = 0; j < 8; ++j)
        atomicAdd(&xout[(size_t)(bg * 8 + j) * DDIM + d], acc[j]);
#undef FMA_CHUNK
#undef WELT
}

// ---------------- per-image segment aggregation (LDS, no global atomics) ----
__global__ __launch_bounds__(256) void aggregate_kernel(
    const float* __restrict__ x, const float* __restrict__ bias,
    const int* __restrict__ seg, float* __restrict__ out)
{
    __shared__ float sums[NSEG * CH];
    __shared__ int   hist[NSEG];
    const int b = blockIdx.x;
    for (int i = threadIdx.x; i < NSEG * CH; i += 256) sums[i] = 0.f;
    for (int i = threadIdx.x; i < NSEG; i += 256) hist[i] = 0;
    __syncthreads();
    for (int p = threadIdx.x; p < HWPIX; p += 256) {
        const int s = seg[b * HWPIX + p];
        atomicAdd(&hist[s], 1);
#pragma unroll
        for (int c = 0; c < CH; ++c) {
            const int d = c * HWPIX + p;
            atomicAdd(&sums[s * CH + c], x[(size_t)b * DDIM + d] + bias[d]);
        }
    }
    __syncthreads();
    for (int i = threadIdx.x; i < NSEG * CH; i += 256) {
        const float cnt = (float)hist[i / CH];
        out[b * NSEG * CH + i] = sums[i] / fmaxf(cnt, 1.f);
    }
}

extern "C" void kernel_launch(void* const* d_in, const int* in_sizes, int n_in,
                              void* d_out, int out_size, void* d_ws, size_t ws_size,
                              hipStream_t stream) {
    const float* X    = (const float*)d_in[0];
    const float* W    = (const float*)d_in[1];
    const float* bias = (const float*)d_in[2];
    const int*   seg  = (const int*)d_in[3];
    float* out = (float*)d_out;

    float* Xt = (float*)d_ws;                          // [KDIM][BATCH] 1.5 MB
    float* x  = Xt + (size_t)KDIM * BATCH;             // [BATCH][DDIM] 1.5 MB

    // x accumulates split-K atomics -> must be zeroed every call
    hipMemsetAsync(x, 0, (size_t)BATCH * DDIM * sizeof(float), stream);

    transpose_x_kernel<<<KDIM * 8 / 256, 256, 0, stream>>>(X, Xt);

    dim3 grid(DDIM / 64, KSPLIT);
    gemm_kernel<<<grid, 256, 0, stream>>>(W, Xt, x);

    aggregate_kernel<<<BATCH, 256, 0, stream>>>(x, bias, seg, out);
}

// Round 3
// 317.970 us; speedup vs baseline: 2.8466x; 1.2859x over previous
//
#include <hip/hip_runtime.h>

// SuperPixelMeanEmbed: x = X@W.T + b (M=32, N=K=12288), then per-superpixel
// channel means. W = 604 MB f32 read once -> ~96 us HBM floor.
//
// R3: R2 was VMEM-request-rate bound (lane<->row => 64 lines per load instr).
// Fix: coalesced global_load_lds(16B) staging of 64x64 W tiles, double
// buffered; pre-swizzled global source (c ^ row&7) so the linear LDS write +
// swizzled ds_read_b128 is bank-conflict-free. X stays wave-uniform s_loads;
// split-K partials via uncontended atomics into x[b,d]; segment aggregation
// per-image in LDS.

namespace {
constexpr int BATCH = 32;
constexpr int CH    = 3;
constexpr int HWPIX = 4096;     // 64*64
constexpr int DDIM  = 12288;
constexpr int KDIM  = 12288;
constexpr int NSEG  = 196;

constexpr int ROWS   = 64;              // rows per block (lane = row)
constexpr int BK     = 64;              // k per LDS tile
constexpr int KSPLIT = 4;
constexpr int KRANGE = KDIM / KSPLIT;   // 3072
constexpr int NTILE  = KRANGE / BK;     // 48
}

// ---------------- X transpose: Xt[k][b] = X[b][k] ----------------
__global__ __launch_bounds__(256) void transpose_x_kernel(
    const float* __restrict__ X, float* __restrict__ Xt)
{
    const int tid = blockIdx.x * 256 + threadIdx.x;
    const int k   = tid >> 3;
    const int b4  = tid & 7;
    float4 v;
    v.x = X[(size_t)(b4 * 4 + 0) * KDIM + k];
    v.y = X[(size_t)(b4 * 4 + 1) * KDIM + k];
    v.z = X[(size_t)(b4 * 4 + 2) * KDIM + k];
    v.w = X[(size_t)(b4 * 4 + 3) * KDIM + k];
    *reinterpret_cast<float4*>(Xt + (size_t)k * BATCH + b4 * 4) = v;
}

__device__ __forceinline__ void gload16(const float* g, float* l) {
    __builtin_amdgcn_global_load_lds(
        (const __attribute__((address_space(1))) void*)g,
        (__attribute__((address_space(3))) void*)l, 16, 0, 0);
}

// ---------------- skinny GEMM, split-K, LDS-staged W ----------------
// grid = (DDIM/64, KSPLIT); block = 256 = 4 waves.
// row = lane; wave w handles batches w*8..w*8+7. All 4 waves share the tile.
__global__ __launch_bounds__(256, 3) void gemm_kernel(
    const float* __restrict__ Wg, const float* __restrict__ Xt,
    float* __restrict__ xout)
{
    __shared__ float lds[2][ROWS * BK];   // 2 x 16 KB

    const int t    = threadIdx.x;
    const int lane = t & 63;
    const int w    = t >> 6;
    const int bg   = __builtin_amdgcn_readfirstlane(w);
    const int d0   = blockIdx.x * ROWS;
    const int kb   = blockIdx.y * KRANGE;

    // staging geometry, per gload instr i: this lane covers
    // row r = w*16 + i*4 + (lane>>4), 16B chunk c = lane&15 of that row.
    // Source chunk pre-swizzled: cs = c ^ (r&7)  (involution; read side XORs
    // the same) -> conflict-free ds_read_b128 at row stride 256B.
    const int rsub = (lane >> 4);
    const int cch  = lane & 15;

    float acc[8];
#pragma unroll
    for (int j = 0; j < 8; ++j) acc[j] = 0.f;

    const float* xbase = Xt + (size_t)kb * BATCH + bg * 8;  // wave-uniform

#define STAGE(buf, tile)                                                     \
    {                                                                        \
        _Pragma("unroll")                                                    \
        for (int i = 0; i < 4; ++i) {                                        \
            const int r  = w * 16 + i * 4 + rsub;                            \
            const int cs = cch ^ (r & 7);                                    \
            const float* src = Wg + (size_t)(d0 + r) * KDIM + kb             \
                             + (tile) * BK + cs * 4;                         \
            float* dst = &lds[buf][(w * 16 + i * 4) * BK];                   \
            gload16(src, dst);                                               \
        }                                                                    \
    }

#define COMPUTE(buf, tile)                                                   \
    {                                                                        \
        const float4* l4 = reinterpret_cast<const float4*>(lds[buf]);        \
        const float* xc0 = xbase + (size_t)(tile) * BK * BATCH;              \
        _Pragma("unroll")                                                    \
        for (int c = 0; c < 16; ++c) {                                       \
            const float4 wv = l4[lane * 16 + (c ^ (lane & 7))];              \
            const float* xc = xc0 + c * 4 * BATCH;                           \
            _Pragma("unroll")                                                \
            for (int j = 0; j < 8; ++j)                                      \
                acc[j] = fmaf(wv.x, xc[0 * BATCH + j], acc[j]);              \
            _Pragma("unroll")                                                \
            for (int j = 0; j < 8; ++j)                                      \
                acc[j] = fmaf(wv.y, xc[1 * BATCH + j], acc[j]);              \
            _Pragma("unroll")                                                \
            for (int j = 0; j < 8; ++j)                                      \
                acc[j] = fmaf(wv.z, xc[2 * BATCH + j], acc[j]);              \
            _Pragma("unroll")                                                \
            for (int j = 0; j < 8; ++j)                                      \
                acc[j] = fmaf(wv.w, xc[3 * BATCH + j], acc[j]);              \
        }                                                                    \
    }

    STAGE(0, 0)
    __syncthreads();                       // buf0 ready (vmcnt(0) drained)
    for (int tile = 0; tile < NTILE; ++tile) {
        const int cur = tile & 1;
        if (tile + 1 < NTILE) STAGE(cur ^ 1, tile + 1)   // async prefetch
        COMPUTE(cur, tile)
        __syncthreads();                   // drain prefetch + retire readers
    }
#undef STAGE
#undef COMPUTE

    // epilogue: wave covers full 64B lines of x[b][d0..d0+63]
#pragma unroll
    for (int j = 0; j < 8; ++j)
        atomicAdd(&xout[(size_t)(bg * 8 + j) * DDIM + d0 + lane], acc[j]);
}

// ---------------- per-image segment aggregation (LDS, no global atomics) ----
__global__ __launch_bounds__(256) void aggregate_kernel(
    const float* __restrict__ x, const float* __restrict__ bias,
    const int* __restrict__ seg, float* __restrict__ out)
{
    __shared__ float sums[NSEG * CH];
    __shared__ int   hist[NSEG];
    const int b = blockIdx.x;
    for (int i = threadIdx.x; i < NSEG * CH; i += 256) sums[i] = 0.f;
    for (int i = threadIdx.x; i < NSEG; i += 256) hist[i] = 0;
    __syncthreads();
    for (int p = threadIdx.x; p < HWPIX; p += 256) {
        const int s = seg[b * HWPIX + p];
        atomicAdd(&hist[s], 1);
#pragma unroll
        for (int c = 0; c < CH; ++c) {
            const int d = c * HWPIX + p;
            atomicAdd(&sums[s * CH + c], x[(size_t)b * DDIM + d] + bias[d]);
        }
    }
    __syncthreads();
    for (int i = threadIdx.x; i < NSEG * CH; i += 256) {
        const float cnt = (float)hist[i / CH];
        out[b * NSEG * CH + i] = sums[i] / fmaxf(cnt, 1.f);
    }
}

extern "C" void kernel_launch(void* const* d_in, const int* in_sizes, int n_in,
                              void* d_out, int out_size, void* d_ws, size_t ws_size,
                              hipStream_t stream) {
    const float* X    = (const float*)d_in[0];
    const float* W    = (const float*)d_in[1];
    const float* bias = (const float*)d_in[2];
    const int*   seg  = (const int*)d_in[3];
    float* out = (float*)d_out;

    float* Xt = (float*)d_ws;                          // [KDIM][BATCH] 1.5 MB
    float* x  = Xt + (size_t)KDIM * BATCH;             // [BATCH][DDIM] 1.5 MB

    // x accumulates split-K atomics -> must be zeroed every call
    hipMemsetAsync(x, 0, (size_t)BATCH * DDIM * sizeof(float), stream);

    transpose_x_kernel<<<KDIM * 8 / 256, 256, 0, stream>>>(X, Xt);

    dim3 grid(DDIM / ROWS, KSPLIT);
    gemm_kernel<<<grid, 256, 0, stream>>>(W, Xt, x);

    aggregate_kernel<<<BATCH, 256, 0, stream>>>(x, bias, seg, out);
}

// Round 4
// 233.653 us; speedup vs baseline: 3.8739x; 1.3609x over previous
//
#include <hip/hip_runtime.h>

// SuperPixelMeanEmbed: x = X@W.T + b (M=32, N=K=12288), then per-superpixel
// channel means. W = 604 MB f32 read once -> HBM floor ~96 us cold, ~60-70 us
// with L3 (256 MB) warm across replays.
//
// R4: R2/R3's hidden stall = X read through the scalar cache (16 KB sL1
// thrashes at 24 KB/CU/tile -> serial ~200cy misses). Fix: stage the X tile
// (64k x 32b = 8 KB) in LDS next to the W tile; X reads become wave-uniform
// LDS broadcasts. Also: split-K now writes plain stores into 4 partial
// buffers (no atomics, no memset); aggregation sums the partials.

namespace {
constexpr int BATCH = 32;
constexpr int CH    = 3;
constexpr int HWPIX = 4096;     // 64*64
constexpr int DDIM  = 12288;
constexpr int KDIM  = 12288;
constexpr int NSEG  = 196;

constexpr int ROWS   = 64;              // rows per block (lane = row)
constexpr int BK     = 64;              // k per LDS tile
constexpr int KSPLIT = 4;
constexpr int KRANGE = KDIM / KSPLIT;   // 3072
constexpr int NTILE  = KRANGE / BK;     // 48
}

// ---------------- X transpose: Xt[k][b] = X[b][k] ----------------
__global__ __launch_bounds__(256) void transpose_x_kernel(
    const float* __restrict__ X, float* __restrict__ Xt)
{
    const int tid = blockIdx.x * 256 + threadIdx.x;
    const int k   = tid >> 3;
    const int b4  = tid & 7;
    float4 v;
    v.x = X[(size_t)(b4 * 4 + 0) * KDIM + k];
    v.y = X[(size_t)(b4 * 4 + 1) * KDIM + k];
    v.z = X[(size_t)(b4 * 4 + 2) * KDIM + k];
    v.w = X[(size_t)(b4 * 4 + 3) * KDIM + k];
    *reinterpret_cast<float4*>(Xt + (size_t)k * BATCH + b4 * 4) = v;
}

__device__ __forceinline__ void gload16(const float* g, float* l) {
    __builtin_amdgcn_global_load_lds(
        (const __attribute__((address_space(1))) void*)g,
        (__attribute__((address_space(3))) void*)l, 16, 0, 0);
}

// ---------------- skinny GEMM, split-K, LDS-staged W and X ----------------
// grid = (DDIM/64, KSPLIT); block = 256 = 4 waves.
// row = lane; wave w handles batches w*8..w*8+7.
__global__ __launch_bounds__(256, 3) void gemm_kernel(
    const float* __restrict__ Wg, const float* __restrict__ Xt,
    float* __restrict__ xpart)
{
    __shared__ float wl[2][ROWS * BK];    // 2 x 16 KB, XOR-swizzled chunks
    __shared__ float xl[2][BK * BATCH];   // 2 x 8 KB, linear [k][b]

    const int t    = threadIdx.x;
    const int lane = t & 63;
    const int w    = t >> 6;
    const int bg   = __builtin_amdgcn_readfirstlane(w);
    const int d0   = blockIdx.x * ROWS;
    const int kb   = blockIdx.y * KRANGE;

    // W staging: per gload i, lane covers row r = w*16+i*4+(lane>>4),
    // 16B chunk slot = lane&15, holding source chunk (lane&15)^(r&7)
    // (involution; read side XORs the same) -> conflict-free ds_read_b128.
    const int rsub = lane >> 4;
    const int cch  = lane & 15;

    float acc[8];
#pragma unroll
    for (int j = 0; j < 8; ++j) acc[j] = 0.f;

    const float* xsrc = Xt + (size_t)kb * BATCH;   // tile t: + t*BK*BATCH

#define STAGE(buf, tile)                                                     \
    {                                                                        \
        _Pragma("unroll")                                                    \
        for (int i = 0; i < 4; ++i) {                                        \
            const int r  = w * 16 + i * 4 + rsub;                            \
            const int cs = cch ^ (r & 7);                                    \
            const float* src = Wg + (size_t)(d0 + r) * KDIM + kb             \
                             + (tile) * BK + cs * 4;                         \
            gload16(src, &wl[buf][(w * 16 + i * 4) * BK]);                   \
        }                                                                    \
        _Pragma("unroll")                                                    \
        for (int i = 0; i < 2; ++i) {                                        \
            const float* src = xsrc + (size_t)(tile) * BK * BATCH            \
                             + (w * 2 + i) * 256 + lane * 4;                 \
            gload16(src, &xl[buf][(w * 2 + i) * 256]);                       \
        }                                                                    \
    }

#define COMPUTE(buf)                                                         \
    {                                                                        \
        const float4* w4 = reinterpret_cast<const float4*>(wl[buf]);         \
        const float4* x4 = reinterpret_cast<const float4*>(xl[buf]);         \
        _Pragma("unroll")                                                    \
        for (int c = 0; c < 16; ++c) {                                       \
            const float4 wv = w4[lane * 16 + (c ^ (lane & 7))];              \
            _Pragma("unroll")                                                \
            for (int e = 0; e < 4; ++e) {                                    \
                const float  we = (e == 0) ? wv.x : (e == 1) ? wv.y          \
                                : (e == 2) ? wv.z : wv.w;                    \
                const float4 xa = x4[(c * 4 + e) * 8 + bg * 2];              \
                const float4 xb = x4[(c * 4 + e) * 8 + bg * 2 + 1];          \
                acc[0] = fmaf(we, xa.x, acc[0]);                             \
                acc[1] = fmaf(we, xa.y, acc[1]);                             \
                acc[2] = fmaf(we, xa.z, acc[2]);                             \
                acc[3] = fmaf(we, xa.w, acc[3]);                             \
                acc[4] = fmaf(we, xb.x, acc[4]);                             \
                acc[5] = fmaf(we, xb.y, acc[5]);                             \
                acc[6] = fmaf(we, xb.z, acc[6]);                             \
                acc[7] = fmaf(we, xb.w, acc[7]);                             \
            }                                                                \
        }                                                                    \
    }

    STAGE(0, 0)
    __syncthreads();                       // buf0 ready (vmcnt drained at bar)
    for (int tile = 0; tile < NTILE; ++tile) {
        const int cur = tile & 1;
        if (tile + 1 < NTILE) STAGE(cur ^ 1, tile + 1)   // async prefetch
        COMPUTE(cur)
        __syncthreads();                   // drain prefetch + retire readers
    }
#undef STAGE
#undef COMPUTE

    // plain stores into this k-split's partial buffer; wave covers 256B lines
    float* dst = xpart + ((size_t)blockIdx.y * BATCH + bg * 8) * DDIM + d0 + lane;
#pragma unroll
    for (int j = 0; j < 8; ++j)
        dst[(size_t)j * DDIM] = acc[j];
}

// ---------------- segment aggregation: one block per (image, channel) ------
__global__ __launch_bounds__(256) void aggregate_kernel(
    const float* __restrict__ xpart, const float* __restrict__ bias,
    const int* __restrict__ seg, float* __restrict__ out)
{
    __shared__ float sums[NSEG];
    __shared__ int   hist[NSEG];
    const int b = blockIdx.x / CH;
    const int c = blockIdx.x % CH;
    for (int i = threadIdx.x; i < NSEG; i += 256) { sums[i] = 0.f; hist[i] = 0; }
    __syncthreads();
    const size_t base = (size_t)b * DDIM + c * HWPIX;
    for (int p = threadIdx.x; p < HWPIX; p += 256) {
        const int s = seg[b * HWPIX + p];
        float v = bias[c * HWPIX + p];
#pragma unroll
        for (int ks = 0; ks < KSPLIT; ++ks)
            v += xpart[(size_t)ks * BATCH * DDIM + base + p];
        atomicAdd(&hist[s], 1);
        atomicAdd(&sums[s], v);
    }
    __syncthreads();
    for (int s = threadIdx.x; s < NSEG; s += 256)
        out[(b * NSEG + s) * CH + c] = sums[s] / fmaxf((float)hist[s], 1.f);
}

extern "C" void kernel_launch(void* const* d_in, const int* in_sizes, int n_in,
                              void* d_out, int out_size, void* d_ws, size_t ws_size,
                              hipStream_t stream) {
    const float* X    = (const float*)d_in[0];
    const float* W    = (const float*)d_in[1];
    const float* bias = (const float*)d_in[2];
    const int*   seg  = (const int*)d_in[3];
    float* out = (float*)d_out;

    float* Xt    = (float*)d_ws;                       // [KDIM][BATCH] 1.5 MB
    float* xpart = Xt + (size_t)KDIM * BATCH;          // [KSPLIT][B][D] 6 MB

    transpose_x_kernel<<<KDIM * 8 / 256, 256, 0, stream>>>(X, Xt);

    dim3 grid(DDIM / ROWS, KSPLIT);
    gemm_kernel<<<grid, 256, 0, stream>>>(W, Xt, xpart);

    aggregate_kernel<<<BATCH * CH, 256, 0, stream>>>(xpart, bias, seg, out);
}

// Round 5
// 141.313 us; speedup vs baseline: 6.4052x; 1.6534x over previous
//
#include <hip/hip_runtime.h>

// SuperPixelMeanEmbed: x = X@W.T + b (M=32, N=K=12288), then per-superpixel
// channel means. W = 604 MB f32 read once -> HBM floor ~96 us (less if L3
// keeps part of W warm across replays).
//
// R5: R4 was LDS-issue-bound (X broadcast reads = 4 FMAs/read). Fix: MFMA.
// W converted f32->bf16 on the fly at fragment build (W still read once as
// f32); X pre-converted to bf16 (0.75 MB, stays in its original [b][k]
// layout = exactly the B-fragment layout). Per 64x64 tile per wave: 8
// ds_read_b128 + 4 mfma_f32_16x16x32_bf16 vs R4's 144 LDS reads + 512 FMAs.
// Pure HBM-bound by construction.

#include <hip/hip_bf16.h>

typedef __attribute__((ext_vector_type(8))) short short8;
typedef __attribute__((ext_vector_type(4))) float f32x4;

namespace {
constexpr int BATCH = 32;
constexpr int CH    = 3;
constexpr int HWPIX = 4096;     // 64*64
constexpr int DDIM  = 12288;
constexpr int KDIM  = 12288;
constexpr int NSEG  = 196;

constexpr int ROWS = 64;        // d-rows per block (wave w owns rows w*16..+15)
constexpr int BK   = 64;        // k per LDS tile
}

__device__ __forceinline__ ushort bf16rne(float f) {
    union { float f; unsigned u; } v; v.f = f;
    const unsigned r = v.u + 0x7fffu + ((v.u >> 16) & 1u);   // round-nearest-even
    return (ushort)(r >> 16);
}

__device__ __forceinline__ void gload16(const void* g, void* l) {
    __builtin_amdgcn_global_load_lds(
        (const __attribute__((address_space(1))) void*)g,
        (__attribute__((address_space(3))) void*)l, 16, 0, 0);
}

// ---------------- X f32 -> bf16, same [b][k] layout ----------------
__global__ __launch_bounds__(256) void convert_x_kernel(
    const float* __restrict__ X, ushort* __restrict__ Xb)
{
    const int i = (blockIdx.x * 256 + threadIdx.x) * 4;
    const float4 v = *reinterpret_cast<const float4*>(X + i);
    ushort4 o;
    o.x = bf16rne(v.x); o.y = bf16rne(v.y); o.z = bf16rne(v.z); o.w = bf16rne(v.w);
    *reinterpret_cast<ushort4*>(Xb + i) = o;
}

// ---------------- MFMA skinny GEMM, split-K ----------------
// grid = (DDIM/64, KSPLIT); block 256 = 4 waves. Wave w computes the
// 16(d) x 32(batch) output tile for rows d0+w*16..+15 over its k-range.
// LDS: W tile f32 [64r][64k] (16 KB) + X tile bf16 [32b][64k] (4 KB), x2 buf.
// Both staged by global_load_lds with pre-swizzled source chunks
// (chunk ^= row&7, 16B granules); reads XOR the same -> conflict-free.
template<int KSPLIT>
__global__ __launch_bounds__(256, 4) void gemm_kernel(
    const float* __restrict__ Wg, const ushort* __restrict__ Xb,
    float* __restrict__ xpart)
{
    constexpr int KRANGE = KDIM / KSPLIT;
    constexpr int NTILE  = KRANGE / BK;

    __shared__ float  wl[2][ROWS * BK];    // 2 x 16 KB
    __shared__ ushort xl[2][BATCH * BK];   // 2 x 4 KB

    const int t    = threadIdx.x;
    const int lane = t & 63;
    const int w    = t >> 6;
    const int d0   = blockIdx.x * ROWS;
    const int kb   = blockIdx.y * KRANGE;

    // staging geometry
    const int rsub = lane >> 4;            // W: sub-row within 4-row gload group
    const int cch  = lane & 15;            // W: 16B chunk slot (16 per 256B row)
    const int xrow = w * 8 + (lane >> 3);  // X: b-row (8 rows/wave, 128B each)
    const int xch  = lane & 7;             // X: 16B chunk slot (8 per row)

    f32x4 acc[2];
#pragma unroll
    for (int nt = 0; nt < 2; ++nt) acc[nt] = (f32x4)(0.f);

#define STAGE(buf, tile)                                                     \
    {                                                                        \
        const int k0 = kb + (tile) * BK;                                     \
        _Pragma("unroll")                                                    \
        for (int i = 0; i < 4; ++i) {                                        \
            const int r  = w * 16 + i * 4 + rsub;                            \
            const int cs = cch ^ (r & 7);                                    \
            gload16(Wg + (size_t)(d0 + r) * KDIM + k0 + cs * 4,              \
                    &wl[buf][(w * 16 + i * 4) * BK]);                        \
        }                                                                    \
        {                                                                    \
            const int cs = xch ^ (xrow & 7);                                 \
            gload16(Xb + (size_t)xrow * KDIM + k0 + cs * 8,                  \
                    &xl[buf][(w * 8) * BK]);                                 \
        }                                                                    \
    }

#define COMPUTE(buf)                                                         \
    {                                                                        \
        _Pragma("unroll")                                                    \
        for (int kk = 0; kk < 2; ++kk) {                                     \
            const int R  = w * 16 + (lane & 15);                             \
            const int c0 = kk * 8 + (lane >> 4) * 2;  /* 4-f32 chunk idx */  \
            const float4 f0 = *reinterpret_cast<const float4*>(              \
                &wl[buf][R * BK + ((c0    ) ^ (lane & 7)) * 4]);             \
            const float4 f1 = *reinterpret_cast<const float4*>(              \
                &wl[buf][R * BK + ((c0 + 1) ^ (lane & 7)) * 4]);             \
            short8 a;                                                        \
            a[0] = (short)bf16rne(f0.x); a[1] = (short)bf16rne(f0.y);        \
            a[2] = (short)bf16rne(f0.z); a[3] = (short)bf16rne(f0.w);        \
            a[4] = (short)bf16rne(f1.x); a[5] = (short)bf16rne(f1.y);        \
            a[6] = (short)bf16rne(f1.z); a[7] = (short)bf16rne(f1.w);        \
            _Pragma("unroll")                                                \
            for (int nt = 0; nt < 2; ++nt) {                                 \
                const int b  = nt * 16 + (lane & 15);                        \
                const int xc = (kk * 4 + (lane >> 4)) ^ (b & 7);             \
                const short8 bb = *reinterpret_cast<const short8*>(          \
                    &xl[buf][b * BK + xc * 8]);                              \
                acc[nt] = __builtin_amdgcn_mfma_f32_16x16x32_bf16(           \
                    a, bb, acc[nt], 0, 0, 0);                                \
            }                                                                \
        }                                                                    \
    }

    STAGE(0, 0)
    __syncthreads();                       // vmcnt drained at barrier
    for (int tile = 0; tile < NTILE; ++tile) {
        const int cur = tile & 1;
        if (tile + 1 < NTILE) STAGE(cur ^ 1, tile + 1)   // async prefetch
        COMPUTE(cur)
        __syncthreads();                   // drain prefetch + retire readers
    }
#undef STAGE
#undef COMPUTE

    // epilogue: D layout col=lane&15 (batch), row=(lane>>4)*4+reg (d)
    float* xp = xpart + (size_t)blockIdx.y * BATCH * DDIM;
#pragma unroll
    for (int nt = 0; nt < 2; ++nt) {
        const int b = nt * 16 + (lane & 15);
        const int m = d0 + w * 16 + (lane >> 4) * 4;
#pragma unroll
        for (int r = 0; r < 4; ++r)
            xp[(size_t)b * DDIM + m + r] = acc[nt][r];
    }
}

// ---------------- segment aggregation: one block per (image, channel) ------
template<int KSPLIT>
__global__ __launch_bounds__(256) void aggregate_kernel(
    const float* __restrict__ xpart, const float* __restrict__ bias,
    const int* __restrict__ seg, float* __restrict__ out)
{
    __shared__ float sums[NSEG];
    __shared__ int   hist[NSEG];
    const int b = blockIdx.x / CH;
    const int c = blockIdx.x % CH;
    for (int i = threadIdx.x; i < NSEG; i += 256) { sums[i] = 0.f; hist[i] = 0; }
    __syncthreads();
    const size_t base = (size_t)b * DDIM + c * HWPIX;
    for (int p = threadIdx.x; p < HWPIX; p += 256) {
        const int s = seg[b * HWPIX + p];
        float v = bias[c * HWPIX + p];
#pragma unroll
        for (int ks = 0; ks < KSPLIT; ++ks)
            v += xpart[(size_t)ks * BATCH * DDIM + base + p];
        atomicAdd(&hist[s], 1);
        atomicAdd(&sums[s], v);
    }
    __syncthreads();
    for (int s = threadIdx.x; s < NSEG; s += 256)
        out[(b * NSEG + s) * CH + c] = sums[s] / fmaxf((float)hist[s], 1.f);
}

extern "C" void kernel_launch(void* const* d_in, const int* in_sizes, int n_in,
                              void* d_out, int out_size, void* d_ws, size_t ws_size,
                              hipStream_t stream) {
    const float* X    = (const float*)d_in[0];
    const float* W    = (const float*)d_in[1];
    const float* bias = (const float*)d_in[2];
    const int*   seg  = (const int*)d_in[3];
    float* out = (float*)d_out;

    ushort* Xb    = (ushort*)d_ws;                         // [32][12288] bf16, 0.75 MB
    float*  xpart = (float*)(Xb + (size_t)BATCH * KDIM);   // [KSPLIT][32][12288]

    convert_x_kernel<<<BATCH * KDIM / (256 * 4), 256, 0, stream>>>(X, Xb);

    const size_t need8 = (size_t)BATCH * KDIM * 2 + (size_t)8 * BATCH * DDIM * 4;
    if (ws_size >= need8) {
        dim3 grid(DDIM / ROWS, 8);
        gemm_kernel<8><<<grid, 256, 0, stream>>>(W, Xb, xpart);
        aggregate_kernel<8><<<BATCH * CH, 256, 0, stream>>>(xpart, bias, seg, out);
    } else {
        dim3 grid(DDIM / ROWS, 4);
        gemm_kernel<4><<<grid, 256, 0, stream>>>(W, Xb, xpart);
        aggregate_kernel<4><<<BATCH * CH, 256, 0, stream>>>(xpart, bias, seg, out);
    }
}

// Round 6
// 134.952 us; speedup vs baseline: 6.7072x; 1.0471x over previous
//
#include <hip/hip_runtime.h>

// SuperPixelMeanEmbed: x = X@W.T + b (M=32, N=K=12288), then per-superpixel
// channel means. W = 604 MB f32 read once -> HBM floor ~92 us at the
// measured 6.6 TB/s streaming rate (less where L3 keeps W warm).
//
// R6: R5 was HBM-bound but the __syncthreads double-buffer drained vmcnt(0)
// every tile (per-block fetch collapses to 20 KB bursts). Fix (T3/T4):
// counted s_waitcnt vmcnt(5) + raw s_barrier; STAGE(t+2) issues before the
// wait on t+1's loads -> 2 tiles (40 KB/block) in flight with 2 buffers.
// Aggregate reads vectorized (int4/float4).

#include <hip/hip_bf16.h>

typedef __attribute__((ext_vector_type(8))) short short8;
typedef __attribute__((ext_vector_type(4))) float f32x4;

namespace {
constexpr int BATCH = 32;
constexpr int CH    = 3;
constexpr int HWPIX = 4096;     // 64*64
constexpr int DDIM  = 12288;
constexpr int KDIM  = 12288;
constexpr int NSEG  = 196;

constexpr int ROWS = 64;        // d-rows per block (wave w owns rows w*16..+15)
constexpr int BK   = 64;        // k per LDS tile
}

__device__ __forceinline__ ushort bf16rne(float f) {
    union { float f; unsigned u; } v; v.f = f;
    const unsigned r = v.u + 0x7fffu + ((v.u >> 16) & 1u);   // round-nearest-even
    return (ushort)(r >> 16);
}

__device__ __forceinline__ void gload16(const void* g, void* l) {
    __builtin_amdgcn_global_load_lds(
        (const __attribute__((address_space(1))) void*)g,
        (__attribute__((address_space(3))) void*)l, 16, 0, 0);
}

// ---------------- X f32 -> bf16, same [b][k] layout ----------------
__global__ __launch_bounds__(256) void convert_x_kernel(
    const float* __restrict__ X, ushort* __restrict__ Xb)
{
    const int i = (blockIdx.x * 256 + threadIdx.x) * 4;
    const float4 v = *reinterpret_cast<const float4*>(X + i);
    ushort4 o;
    o.x = bf16rne(v.x); o.y = bf16rne(v.y); o.z = bf16rne(v.z); o.w = bf16rne(v.w);
    *reinterpret_cast<ushort4*>(Xb + i) = o;
}

// ---------------- MFMA skinny GEMM, split-K ----------------
// grid = (DDIM/64, KSPLIT); block 256 = 4 waves. Wave w computes the
// 16(d) x 32(batch) output tile for rows d0+w*16..+15 over its k-range.
// LDS: W tile f32 [64r][64k] (16 KB) + X tile bf16 [32b][64k] (4 KB), x2 buf.
// Both staged by global_load_lds with pre-swizzled source chunks
// (chunk ^= row&7, 16B granules); reads XOR the same -> conflict-free.
template<int KSPLIT>
__global__ __launch_bounds__(256, 4) void gemm_kernel(
    const float* __restrict__ Wg, const ushort* __restrict__ Xb,
    float* __restrict__ xpart)
{
    constexpr int KRANGE = KDIM / KSPLIT;
    constexpr int NTILE  = KRANGE / BK;

    __shared__ float  wl[2][ROWS * BK];    // 2 x 16 KB
    __shared__ ushort xl[2][BATCH * BK];   // 2 x 4 KB

    const int t    = threadIdx.x;
    const int lane = t & 63;
    const int w    = t >> 6;
    const int d0   = blockIdx.x * ROWS;
    const int kb   = blockIdx.y * KRANGE;

    // staging geometry
    const int rsub = lane >> 4;            // W: sub-row within 4-row gload group
    const int cch  = lane & 15;            // W: 16B chunk slot (16 per 256B row)
    const int xrow = w * 8 + (lane >> 3);  // X: b-row (8 rows/wave, 128B each)
    const int xch  = lane & 7;             // X: 16B chunk slot (8 per row)

    f32x4 acc[2];
#pragma unroll
    for (int nt = 0; nt < 2; ++nt) acc[nt] = (f32x4)(0.f);

#define STAGE(buf, tile)                                                     \
    {                                                                        \
        const int k0 = kb + (tile) * BK;                                     \
        _Pragma("unroll")                                                    \
        for (int i = 0; i < 4; ++i) {                                        \
            const int r  = w * 16 + i * 4 + rsub;                            \
            const int cs = cch ^ (r & 7);                                    \
            gload16(Wg + (size_t)(d0 + r) * KDIM + k0 + cs * 4,              \
                    &wl[buf][(w * 16 + i * 4) * BK]);                        \
        }                                                                    \
        {                                                                    \
            const int cs = xch ^ (xrow & 7);                                 \
            gload16(Xb + (size_t)xrow * KDIM + k0 + cs * 8,                  \
                    &xl[buf][(w * 8) * BK]);                                 \
        }                                                                    \
    }

#define COMPUTE(buf)                                                         \
    {                                                                        \
        _Pragma("unroll")                                                    \
        for (int kk = 0; kk < 2; ++kk) {                                     \
            const int R  = w * 16 + (lane & 15);                             \
            const int c0 = kk * 8 + (lane >> 4) * 2;  /* 4-f32 chunk idx */  \
            const float4 f0 = *reinterpret_cast<const float4*>(              \
                &wl[buf][R * BK + ((c0    ) ^ (lane & 7)) * 4]);             \
            const float4 f1 = *reinterpret_cast<const float4*>(              \
                &wl[buf][R * BK + ((c0 + 1) ^ (lane & 7)) * 4]);             \
            short8 a;                                                        \
            a[0] = (short)bf16rne(f0.x); a[1] = (short)bf16rne(f0.y);        \
            a[2] = (short)bf16rne(f0.z); a[3] = (short)bf16rne(f0.w);        \
            a[4] = (short)bf16rne(f1.x); a[5] = (short)bf16rne(f1.y);        \
            a[6] = (short)bf16rne(f1.z); a[7] = (short)bf16rne(f1.w);        \
            _Pragma("unroll")                                                \
            for (int nt = 0; nt < 2; ++nt) {                                 \
                const int b  = nt * 16 + (lane & 15);                        \
                const int xc = (kk * 4 + (lane >> 4)) ^ (b & 7);             \
                const short8 bb = *reinterpret_cast<const short8*>(          \
                    &xl[buf][b * BK + xc * 8]);                              \
                acc[nt] = __builtin_amdgcn_mfma_f32_16x16x32_bf16(           \
                    a, bb, acc[nt], 0, 0, 0);                                \
            }                                                                \
        }                                                                    \
    }

    // prologue: two tiles in flight
    STAGE(0, 0)
    STAGE(1, 1)
    for (int tile = 0; tile < NTILE; ++tile) {
        const int cur = tile & 1;
        // wait current tile's 5 loads; keep next tile's 5 in flight
        if (tile + 1 < NTILE) {
            asm volatile("s_waitcnt vmcnt(5)" ::: "memory");
        } else {
            asm volatile("s_waitcnt vmcnt(0)" ::: "memory");
        }
        __builtin_amdgcn_s_barrier();          // all waves' quarters landed
        asm volatile("" ::: "memory");
        COMPUTE(cur)
        asm volatile("s_waitcnt lgkmcnt(0)" ::: "memory");  // LDS reads retired
        __builtin_amdgcn_s_barrier();          // safe to overwrite cur
        asm volatile("" ::: "memory");
        if (tile + 2 < NTILE) STAGE(cur, tile + 2)   // before waiting on t+1
    }
#undef STAGE
#undef COMPUTE

    // epilogue: D layout col=lane&15 (batch), row=(lane>>4)*4+reg (d)
    float* xp = xpart + (size_t)blockIdx.y * BATCH * DDIM;
#pragma unroll
    for (int nt = 0; nt < 2; ++nt) {
        const int b = nt * 16 + (lane & 15);
        const int m = d0 + w * 16 + (lane >> 4) * 4;
#pragma unroll
        for (int r = 0; r < 4; ++r)
            xp[(size_t)b * DDIM + m + r] = acc[nt][r];
    }
}

// ---------------- segment aggregation: one block per (image, channel) ------
template<int KSPLIT>
__global__ __launch_bounds__(256) void aggregate_kernel(
    const float* __restrict__ xpart, const float* __restrict__ bias,
    const int* __restrict__ seg, float* __restrict__ out)
{
    __shared__ float sums[NSEG];
    __shared__ int   hist[NSEG];
    const int b = blockIdx.x / CH;
    const int c = blockIdx.x % CH;
    for (int i = threadIdx.x; i < NSEG; i += 256) { sums[i] = 0.f; hist[i] = 0; }
    __syncthreads();
    const size_t base = (size_t)b * DDIM + c * HWPIX;
#pragma unroll
    for (int it = 0; it < HWPIX / 1024; ++it) {
        const int p0 = it * 1024 + threadIdx.x * 4;
        const int4 s4 = *reinterpret_cast<const int4*>(seg + b * HWPIX + p0);
        float4 v = *reinterpret_cast<const float4*>(bias + c * HWPIX + p0);
#pragma unroll
        for (int ks = 0; ks < KSPLIT; ++ks) {
            const float4 xv = *reinterpret_cast<const float4*>(
                xpart + (size_t)ks * BATCH * DDIM + base + p0);
            v.x += xv.x; v.y += xv.y; v.z += xv.z; v.w += xv.w;
        }
        atomicAdd(&hist[s4.x], 1); atomicAdd(&sums[s4.x], v.x);
        atomicAdd(&hist[s4.y], 1); atomicAdd(&sums[s4.y], v.y);
        atomicAdd(&hist[s4.z], 1); atomicAdd(&sums[s4.z], v.z);
        atomicAdd(&hist[s4.w], 1); atomicAdd(&sums[s4.w], v.w);
    }
    __syncthreads();
    for (int s = threadIdx.x; s < NSEG; s += 256)
        out[(b * NSEG + s) * CH + c] = sums[s] / fmaxf((float)hist[s], 1.f);
}

extern "C" void kernel_launch(void* const* d_in, const int* in_sizes, int n_in,
                              void* d_out, int out_size, void* d_ws, size_t ws_size,
                              hipStream_t stream) {
    const float* X    = (const float*)d_in[0];
    const float* W    = (const float*)d_in[1];
    const float* bias = (const float*)d_in[2];
    const int*   seg  = (const int*)d_in[3];
    float* out = (float*)d_out;

    ushort* Xb    = (ushort*)d_ws;                         // [32][12288] bf16, 0.75 MB
    float*  xpart = (float*)(Xb + (size_t)BATCH * KDIM);   // [KSPLIT][32][12288]

    convert_x_kernel<<<BATCH * KDIM / (256 * 4), 256, 0, stream>>>(X, Xb);

    const size_t need8 = (size_t)BATCH * KDIM * 2 + (size_t)8 * BATCH * DDIM * 4;
    if (ws_size >= need8) {
        dim3 grid(DDIM / ROWS, 8);
        gemm_kernel<8><<<grid, 256, 0, stream>>>(W, Xb, xpart);
        aggregate_kernel<8><<<BATCH * CH, 256, 0, stream>>>(xpart, bias, seg, out);
    } else {
        dim3 grid(DDIM / ROWS, 4);
        gemm_kernel<4><<<grid, 256, 0, stream>>>(W, Xb, xpart);
        aggregate_kernel<4><<<BATCH * CH, 256, 0, stream>>>(xpart, bias, seg, out);
    }
}